// Round 3
// baseline (837.822 us; speedup 1.0000x reference)
//
#include <hip/hip_runtime.h>
#include <math.h>

#define NN    768
#define CS    384
#define INF_  100000.0f

typedef __attribute__((ext_vector_type(8))) short s16x8;
typedef __attribute__((ext_vector_type(4))) float f32x4;

// ws offsets in floats
#define OFF_Q       0         // 768*192
#define OFF_K       147456    // 768*192
#define OFF_V       294912    // 768*192
#define OFF_QPRAW   442368    // 768*144
#define OFF_KVPRAW  552960    // 768*432
#define OFF_QPTS    884736    // 768*48*3
#define OFF_KPTS    995328    // 768*48*3
#define OFF_VPTS    1105920   // 768*96*3
#define OFF_KT      1327104   // 192*768 (K transposed [h*16+c][k])
#define OFF_KPT     1474560   // 144*768 (K_pts transposed [h*12+r][k])
#define OFF_CAT     8414208   // 768*2112

__device__ __forceinline__ unsigned short f2bf(float x) {
  unsigned u = __float_as_uint(x) + 0x8000u;   // round-to-nearest-ish
  return (unsigned short)(u >> 16);
}
__device__ __forceinline__ unsigned pk2(float a, float b) {
  return (unsigned)f2bf(a) | ((unsigned)f2bf(b) << 16);
}

// ---------------------------------------------------------------- K1: projections (unchanged)
__global__ void __launch_bounds__(256)
k1_proj(const float* __restrict__ s,
        const float* __restrict__ Wq,  const float* __restrict__ bq,
        const float* __restrict__ Wqp, const float* __restrict__ bqp,
        const float* __restrict__ Wkv, const float* __restrict__ bkv,
        const float* __restrict__ Wkvp,const float* __restrict__ bkvp,
        float* __restrict__ ws) {
  __shared__ float s_lds[8][CS];
  const int n0 = blockIdx.y * 8;
  const int j0 = blockIdx.x * 32;
  const int t  = threadIdx.x;

  const float4* s4  = (const float4*)(s + (size_t)n0 * CS);
  float4*       sl4 = (float4*)(&s_lds[0][0]);
  for (int i = t; i < 768; i += 256) sl4[i] = s4[i];
  __syncthreads();

  const int m = t >> 5;
  const int j = j0 + (t & 31);

  const float* W; const float* bv; int jj, ncols;
  if (j < 192)      { W = Wq;   bv = bq;   jj = j;       ncols = 192; }
  else if (j < 576) { W = Wkv;  bv = bkv;  jj = j - 192; ncols = 384; }
  else if (j < 720) { W = Wqp;  bv = bqp;  jj = j - 576; ncols = 144; }
  else              { W = Wkvp; bv = bkvp; jj = j - 720; ncols = 432; }

  float acc = bv[jj];
  const float* Wp = W + jj;
  for (int c = 0; c < CS; ++c) acc += s_lds[m][c] * Wp[(size_t)c * ncols];

  const int n = n0 + m;
  if (j < 192) {
    (ws + OFF_Q)[n * 192 + jj] = acc;
  } else if (j < 576) {
    int h = jj >> 5, c = jj & 31;
    if (c < 16) (ws + OFF_K)[n * 192 + h * 16 + c] = acc;
    else        (ws + OFF_V)[n * 192 + h * 16 + (c - 16)] = acc;
  } else if (j < 720) {
    (ws + OFF_QPRAW)[n * 144 + jj] = acc;
  } else {
    (ws + OFF_KVPRAW)[n * 432 + jj] = acc;
  }
}

// ---------------------------------------------------------------- K2: rotate points (unchanged)
__global__ void __launch_bounds__(256)
k2_rot(const float* __restrict__ rot, const float* __restrict__ trans,
       float* __restrict__ ws) {
  const int idx = blockIdx.x * 256 + threadIdx.x;
  const int n = idx / 192;
  const int r = idx % 192;
  const float* R = rot + n * 9;
  const float* T = trans + n * 3;
  if (r < 48) {
    const float* raw = ws + OFF_QPRAW + n * 144;
    float p0 = raw[r], p1 = raw[48 + r], p2 = raw[96 + r];
    float g0 = R[0]*p0 + R[1]*p1 + R[2]*p2 + T[0];
    float g1 = R[3]*p0 + R[4]*p1 + R[5]*p2 + T[1];
    float g2 = R[6]*p0 + R[7]*p1 + R[8]*p2 + T[2];
    float* qp = ws + OFF_QPTS + n * 144 + r * 3;
    qp[0] = g0; qp[1] = g1; qp[2] = g2;
  } else {
    const int r2 = r - 48;
    const float* raw = ws + OFF_KVPRAW + n * 432;
    float p0 = raw[r2], p1 = raw[144 + r2], p2 = raw[288 + r2];
    float g0 = R[0]*p0 + R[1]*p1 + R[2]*p2 + T[0];
    float g1 = R[3]*p0 + R[4]*p1 + R[5]*p2 + T[1];
    float g2 = R[6]*p0 + R[7]*p1 + R[8]*p2 + T[2];
    const int h = r2 / 12, p = r2 % 12;
    if (p < 4) {
      float* kp = ws + OFF_KPTS + n * 144 + (h * 4 + p) * 3;
      kp[0] = g0; kp[1] = g1; kp[2] = g2;
    } else {
      float* vp = ws + OFF_VPTS + n * 288 + (h * 8 + (p - 4)) * 3;
      vp[0] = g0; vp[1] = g1; vp[2] = g2;
    }
  }
}

// ---------------------------------------------------------------- K2b: transpose K, K_pts to [feat][k]
__global__ void __launch_bounds__(256)
k2b_tr(float* __restrict__ ws) {
  const int i = blockIdx.x * 256 + threadIdx.x;   // 0..258047
  if (i < 147456) {
    const int n = i / 192, cc = i % 192;
    (ws + OFF_KT)[cc * 768 + n] = (ws + OFF_K)[i];
  } else {
    const int i2 = i - 147456;
    const int n = i2 / 144, r = i2 % 144;
    (ws + OFF_KPT)[r * 768 + n] = (ws + OFF_KPTS)[i2];
  }
}

// ---------------------------------------------------------------- K3: fused single-z-pass attention (MFMA)
// One q per block; 12 chunks of 64 k. z staged bf16 in two layouts:
//   zR[k][c]  (row-major, bias B-frags)     stride 136 bf16 (272 B)
//   zT[c][k'] (transposed, o_pair B-frags)  stride 72 bf16 (144 B), k'=pi(k)
// pi(k) = (k%8)*8 + k/8 (involution) makes the transpose writes 16B-contiguous.
// bias = (WbT @ zR^T) via mfma 16x16x32 (A-frags resident), o_pair via mfma
// with A = wT (h-major bf16 w). o/o_pt in VALU with coalesced V/vpts reads.
#define ZT_S 72
#define ZR_S 136
#define WT_S 72
#define WH_S 68
__global__ void __launch_bounds__(256, 3)
k3_fused(const float* __restrict__ z, const float* __restrict__ rot,
         const float* __restrict__ trans, const float* __restrict__ mask,
         const float* __restrict__ Wb, const float* __restrict__ bb,
         const float* __restrict__ hwin, float* __restrict__ ws) {
  const int q = blockIdx.x, t = threadIdx.x;
  const int g   = t >> 6;        // wave id 0..3
  const int kl  = t & 63;        // lane
  const int l15 = kl & 15, lq = kl >> 4;

  __shared__ unsigned short zT[128 * ZT_S];   // 18432 B
  __shared__ unsigned short zR[64 * ZR_S];    // 17408 B
  __shared__ unsigned short wT[16 * WT_S];    // 2304 B (rows 12..15 garbage, discarded)
  __shared__ float wH[12 * WH_S];             // 3264 B
  __shared__ float bias_s[64 * 13];           // 3328 B
  __shared__ float hw_l[12], bb_l[12], lsum[12], linv[12];
  __shared__ float opt_raw[288];

  if (t < 12) {
    hw_l[t] = logf(1.0f + expf(hwin[t])) * 0.13608276348795434f; // softplus*sqrt(1/54)
    bb_l[t] = bb[t];
  }

  // resident bias A-frags: A[m=h][c] = Wb[c][h], h = l15 (rows 12..15 zero)
  s16x8 wbA[4];
  #pragma unroll
  for (int kk = 0; kk < 4; ++kk) {
    #pragma unroll
    for (int j = 0; j < 8; ++j) {
      float v = (l15 < 12) ? Wb[(kk * 32 + lq * 8 + j) * 12 + l15] : 0.0f;
      wbA[kk][j] = (short)f2bf(v);
    }
  }

  const float maskq  = mask[q];
  const float* qrow  = ws + OFF_Q    + q * 192;   // uniform -> s_loads
  const float* qprow = ws + OFF_QPTS + q * 144;
  const float* ktr   = ws + OFF_KT;
  const float* kptr  = ws + OFF_KPT;
  const float* vbase = ws + OFF_V;
  const float* vpbase= ws + OFF_VPTS;
  const float4* zg4  = (const float4*)z + (size_t)q * 24576;

  float l3[3] = {0.f, 0.f, 0.f};
  f32x4 opA = {0.f,0.f,0.f,0.f}, opB = {0.f,0.f,0.f,0.f};  // o_pair acc: n-tiles 2g, 2g+1
  float o_acc = 0.f;                  // t<192: o slot (h=t>>4, c=t&15)
  float pt0 = 0.f, pt1 = 0.f;         // o_pt slots t and 256+t (t<32)
  const int oh  = t >> 4;
  const int ph  = t / 24,        prr = t % 24;
  const int p2s = 256 + t, p2h = p2s / 24;

  for (int k0 = 0; k0 < NN; k0 += 64) {
    __syncthreads();   // prev chunk phase C done before LDS overwrite

    // ---- staging: 64 rows x 128 c fp32 -> bf16, dual layout
    float4 zv[8];
    #pragma unroll
    for (int j = 0; j < 8; ++j) zv[j] = zg4[k0 * 32 + t + 256 * j];
    const int kb = t >> 5, c4 = t & 31;   // thread holds c4 fixed, k = kb+8j
    #pragma unroll
    for (int j = 0; j < 8; ++j) {
      uint2 d;
      d.x = pk2(zv[j].x, zv[j].y);
      d.y = pk2(zv[j].z, zv[j].w);
      *(uint2*)&zR[(kb + 8 * j) * ZR_S + c4 * 4] = d;
    }
    #pragma unroll
    for (int e = 0; e < 4; ++e) {
      // pi(kb+8j) = kb*8 + j  -> j-contiguous 16B store
      uint4 d;
      d.x = pk2(((const float*)&zv[0])[e], ((const float*)&zv[1])[e]);
      d.y = pk2(((const float*)&zv[2])[e], ((const float*)&zv[3])[e]);
      d.z = pk2(((const float*)&zv[4])[e], ((const float*)&zv[5])[e]);
      d.w = pk2(((const float*)&zv[6])[e], ((const float*)&zv[7])[e]);
      *(uint4*)&zT[(c4 * 4 + e) * ZT_S + kb * 8] = d;
    }
    __syncthreads();

    // ---- bias MFMA: wave g -> k-tile g. D[h][k] ends as row=(lq*4+r)=h, col=l15=k
    {
      f32x4 bd = {0.f,0.f,0.f,0.f};
      #pragma unroll
      for (int kk = 0; kk < 4; ++kk) {
        s16x8 bf = *(const s16x8*)&zR[(g * 16 + l15) * ZR_S + kk * 32 + lq * 8];
        bd = __builtin_amdgcn_mfma_f32_16x16x32_bf16(wbA[kk], bf, bd, 0, 0, 0);
      }
      #pragma unroll
      for (int r = 0; r < 4; ++r) {
        const int h = lq * 4 + r;
        if (h < 12) bias_s[(g * 16 + l15) * 13 + h] = bd[r];
      }
    }
    // ---- qk/pt (coalesced transposed reads), independent of bias
    float lg[3];
    {
      const int kg = k0 + kl;
      const float mterm = INF_ * (maskq * mask[kg] - 1.0f);
      #pragma unroll
      for (int j = 0; j < 3; ++j) {
        const int h = g + 4 * j;
        float qk = 0.f;
        #pragma unroll
        for (int c = 0; c < 16; ++c)
          qk += qrow[h * 16 + c] * ktr[(h * 16 + c) * 768 + kg];
        float pt = 0.f;
        #pragma unroll
        for (int r = 0; r < 12; ++r) {
          const float d = qprow[h * 12 + r] - kptr[(h * 12 + r) * 768 + kg];
          pt += d * d;
        }
        lg[j] = 0.14433756729740643f * qk
              + 0.57735026918962576f * bb_l[h]
              - 0.5f * hw_l[h] * pt + mterm;
      }
    }
    __syncthreads();

    // ---- w = exp(logit); store h-major bf16 (wT, pi-order) + k-fast f32 (wH)
    #pragma unroll
    for (int j = 0; j < 3; ++j) {
      const int h = g + 4 * j;
      const float wv = __expf(lg[j] + 0.57735026918962576f * bias_s[kl * 13 + h]);
      l3[j] += wv;
      wH[h * WH_S + kl] = wv;
      wT[h * WT_S + (((kl & 7) << 3) | (kl >> 3))] = f2bf(wv);
    }
    __syncthreads();

    // ---- phase C: o_pair MFMA (all waves), o/o_pt VALU
    #pragma unroll
    for (int kk = 0; kk < 2; ++kk) {
      s16x8 af = *(const s16x8*)&wT[l15 * WT_S + kk * 32 + lq * 8];
      s16x8 b0 = *(const s16x8*)&zT[((2 * g)     * 16 + l15) * ZT_S + kk * 32 + lq * 8];
      opA = __builtin_amdgcn_mfma_f32_16x16x32_bf16(af, b0, opA, 0, 0, 0);
      s16x8 b1 = *(const s16x8*)&zT[((2 * g + 1) * 16 + l15) * ZT_S + kk * 32 + lq * 8];
      opB = __builtin_amdgcn_mfma_f32_16x16x32_bf16(af, b1, opB, 0, 0, 0);
    }
    {
      const float* vpr = vpbase + (size_t)k0 * 288;
      const float* vr  = vbase  + (size_t)k0 * 192;
      #pragma unroll 4
      for (int k4 = 0; k4 < 16; ++k4) {
        const int k = k4 * 4;
        {
          const float4 w4 = *(const float4*)&wH[ph * WH_S + k];
          pt0 += w4.x * vpr[(k    ) * 288 + t] + w4.y * vpr[(k + 1) * 288 + t]
               + w4.z * vpr[(k + 2) * 288 + t] + w4.w * vpr[(k + 3) * 288 + t];
        }
        if (t < 32) {
          const float4 w4 = *(const float4*)&wH[p2h * WH_S + k];
          pt1 += w4.x * vpr[(k    ) * 288 + p2s] + w4.y * vpr[(k + 1) * 288 + p2s]
               + w4.z * vpr[(k + 2) * 288 + p2s] + w4.w * vpr[(k + 3) * 288 + p2s];
        }
        if (t < 192) {
          const float4 w4 = *(const float4*)&wH[oh * WH_S + k];
          o_acc += w4.x * vr[(k    ) * 192 + t] + w4.y * vr[(k + 1) * 192 + t]
                 + w4.z * vr[(k + 2) * 192 + t] + w4.w * vr[(k + 3) * 192 + t];
        }
      }
    }
  }

  // ---- l reduction
  #pragma unroll
  for (int j = 0; j < 3; ++j) {
    float v = l3[j];
    for (int off = 1; off < 64; off <<= 1) v += __shfl_xor(v, off, 64);
    l3[j] = v;
  }
  if (kl == 0) { lsum[g] = l3[0]; lsum[g + 4] = l3[1]; lsum[g + 8] = l3[2]; }
  __syncthreads();
  if (t < 12) linv[t] = 1.0f / lsum[t];
  __syncthreads();

  float* cat = ws + OFF_CAT + (size_t)q * 2112;
  #pragma unroll
  for (int r = 0; r < 4; ++r) {
    const int h = lq * 4 + r;
    if (h < 12) {
      cat[576 + h * 128 + (2 * g)     * 16 + l15] = opA[r] * linv[h];
      cat[576 + h * 128 + (2 * g + 1) * 16 + l15] = opB[r] * linv[h];
    }
  }
  if (t < 192) cat[t] = o_acc * linv[oh];
  opt_raw[t] = pt0 * linv[ph];
  if (t < 32) opt_raw[p2s] = pt1 * linv[p2h];
  __syncthreads();

  if (t < 96) {
    const int h = t >> 3, p = t & 7;
    const float* R = rot + q * 9;
    const float* T = trans + q * 3;
    const float g0 = opt_raw[h * 24 + p * 3 + 0] - T[0];
    const float g1 = opt_raw[h * 24 + p * 3 + 1] - T[1];
    const float g2 = opt_raw[h * 24 + p * 3 + 2] - T[2];
    const float x  = R[0]*g0 + R[3]*g1 + R[6]*g2;
    const float y  = R[1]*g0 + R[4]*g1 + R[7]*g2;
    const float zc = R[2]*g0 + R[5]*g1 + R[8]*g2;
    const int hp = h * 8 + p;
    cat[192 + hp] = x;
    cat[288 + hp] = y;
    cat[384 + hp] = zc;
    cat[480 + hp] = sqrtf(x*x + y*y + zc*zc + 1e-8f);
  }
}

// ---------------------------------------------------------------- K5: out = bout (init), then cat @ Wout (tiled, K-split x4, atomic)
__global__ void __launch_bounds__(256)
k5_init(const float* __restrict__ bout, float* __restrict__ out) {
  const int i = blockIdx.x * 256 + threadIdx.x;  // 294912
  out[i] = bout[i % 384];
}

#define K5_CH 48
__global__ void __launch_bounds__(256)
k5_out(const float* __restrict__ Wout, const float* __restrict__ ws,
       float* __restrict__ out) {
  __shared__ float At[K5_CH * 68];   // [k][m], padded
  __shared__ float Bn[K5_CH * 68];   // [k][n], padded
  const int n0  = blockIdx.x * 64;   // 6
  const int m0  = blockIdx.y * 64;   // 12
  const int ks0 = blockIdx.z * 528;  // 4 K-segments
  const int t = threadIdx.x;
  const int tx = t & 15, ty = t >> 4;
  float acc[4][4] = {{0.f}};

  const float* catg = ws + OFF_CAT;
  for (int kc = 0; kc < 528; kc += K5_CH) {
    __syncthreads();
    #pragma unroll
    for (int ii = 0; ii < 12; ++ii) {            // At: 64m x 48k transposed
      const int i = t + 256 * ii;
      const int m = i / 48, k = i % 48;
      At[k * 68 + m] = catg[(size_t)(m0 + m) * 2112 + ks0 + kc + k];
    }
    #pragma unroll
    for (int ii = 0; ii < 12; ++ii) {            // Bn: 48k x 64n
      const int i = t + 256 * ii;
      const int k = i >> 6, n = i & 63;
      Bn[k * 68 + n] = Wout[(size_t)(ks0 + kc + k) * 384 + n0 + n];
    }
    __syncthreads();
    #pragma unroll 4
    for (int k = 0; k < K5_CH; ++k) {
      const float4 a4 = *(const float4*)&At[k * 68 + ty * 4];
      const float4 b4 = *(const float4*)&Bn[k * 68 + tx * 4];
      acc[0][0] += a4.x * b4.x; acc[0][1] += a4.x * b4.y; acc[0][2] += a4.x * b4.z; acc[0][3] += a4.x * b4.w;
      acc[1][0] += a4.y * b4.x; acc[1][1] += a4.y * b4.y; acc[1][2] += a4.y * b4.z; acc[1][3] += a4.y * b4.w;
      acc[2][0] += a4.z * b4.x; acc[2][1] += a4.z * b4.y; acc[2][2] += a4.z * b4.z; acc[2][3] += a4.z * b4.w;
      acc[3][0] += a4.w * b4.x; acc[3][1] += a4.w * b4.y; acc[3][2] += a4.w * b4.z; acc[3][3] += a4.w * b4.w;
    }
  }
  #pragma unroll
  for (int r = 0; r < 4; ++r)
    #pragma unroll
    for (int c = 0; c < 4; ++c)
      atomicAdd(&out[(size_t)(m0 + ty * 4 + r) * 384 + n0 + tx * 4 + c], acc[r][c]);
}

// ----------------------------------------------------------------
extern "C" void kernel_launch(void* const* d_in, const int* in_sizes, int n_in,
                              void* d_out, int out_size, void* d_ws, size_t ws_size,
                              hipStream_t stream) {
  const float* s     = (const float*)d_in[0];
  const float* z     = (const float*)d_in[1];
  const float* rot   = (const float*)d_in[2];
  const float* trans = (const float*)d_in[3];
  const float* mask  = (const float*)d_in[4];
  const float* Wq    = (const float*)d_in[5];
  const float* bq    = (const float*)d_in[6];
  const float* Wqp   = (const float*)d_in[7];
  const float* bqp   = (const float*)d_in[8];
  const float* Wkv   = (const float*)d_in[9];
  const float* bkv   = (const float*)d_in[10];
  const float* bkvp_w= (const float*)d_in[11];
  const float* bkvp  = (const float*)d_in[12];
  const float* Wb    = (const float*)d_in[13];
  const float* bb    = (const float*)d_in[14];
  const float* hw    = (const float*)d_in[15];
  const float* Wout  = (const float*)d_in[16];
  const float* bout  = (const float*)d_in[17];
  float* out = (float*)d_out;
  float* ws  = (float*)d_ws;

  k1_proj<<<dim3(36, 96), 256, 0, stream>>>(s, Wq, bq, Wqp, bqp, Wkv, bkv, bkvp_w, bkvp, ws);
  k2_rot <<<576, 256, 0, stream>>>(rot, trans, ws);
  k2b_tr <<<1008, 256, 0, stream>>>(ws);
  k3_fused<<<NN, 256, 0, stream>>>(z, rot, trans, mask, Wb, bb, hw, ws);
  k5_init<<<1152, 256, 0, stream>>>(bout, out);
  k5_out<<<dim3(6, 12, 4), 256, 0, stream>>>(Wout, ws, out);
}